// Round 13
// baseline (62.815 us; speedup 1.0000x reference)
//
#include <hip/hip_runtime.h>
#include <math.h>

#define NCH 64

typedef __bf16 bf16x8 __attribute__((ext_vector_type(8)));
typedef float f32x4 __attribute__((ext_vector_type(4)));

__global__ void ab_zero(float* __restrict__ ws) {
    int i = blockIdx.x * blockDim.x + threadIdx.x;
    if (i < NCH * 10) ws[i] = 0.0f;
}

__device__ __forceinline__ void glds16(const void* g, void* l) {
    __builtin_amdgcn_global_load_lds(
        (const __attribute__((address_space(1))) void*)g,
        (__attribute__((address_space(3))) void*)l, 16, 0, 0);
}

// R5 config (occ2, grid 512, glds double-buffer, separate Ds finale) with ONE
// structural delta: issue-order swap. Per body: [stage(k+1) -> counted
// vmcnt(7) -> asm ds_read(cur) -> lgkmcnt(0)+sched_barrier -> compute].
// Staging for tile k+1 is in flight DURING the wait for tile k, turning the
// per-wave period from L into (L+E)/2. Counted wait invariant: each body
// issues exactly 7 VMEM ops (4 glds + 3 rp), so vmcnt(7) drains everything
// older (tile k's group) while keeping the just-issued group in flight.
// Unroll x2: literal LDS offsets (0/4096) + alternating P/Q rp sets (no
// register copies that would force an early rp wait before the stage).
__global__ __launch_bounds__(256, 2) void ab_main(
    const float* __restrict__ h, const float* __restrict__ rp,
    const float* __restrict__ W, float* __restrict__ ws, int N)
{
    const int lane = threadIdx.x & 63;
    const int wid  = threadIdx.x >> 6;
    const int c = lane & 15;   // MFMA row/col within 16
    const int g = lane >> 4;   // k-slot group
    const int gwave = blockIdx.x * 4 + wid;
    const int nwave = gridDim.x * 4;

    __shared__ char  ldsb[4][2][4096];   // per-wave double-buffered h tile
    __shared__ float Ds[4][NCH * 10];    // separate reduce buffer (proven)

    // W fragments in registers (loop-invariant): B[j,k]=W[k][j]
    bf16x8 Bf[4][2];
#pragma unroll
    for (int t = 0; t < 4; ++t)
#pragma unroll
      for (int jb = 0; jb < 2; ++jb) {
        const float* wp = W + (t * 16 + c) * NCH + jb * 32 + g * 8;
        f32x4 w0 = *(const f32x4*)wp;
        f32x4 w1 = *(const f32x4*)(wp + 4);
#pragma unroll
        for (int e = 0; e < 4; ++e) { Bf[t][jb][e] = (__bf16)w0[e]; Bf[t][jb][4 + e] = (__bf16)w1[e]; }
      }

    // loop-invariant asm ds_read addresses (buffer 0; buffer 1 via offset:4096)
    unsigned a0r, a1r, a2r, a3r;
    {
        int a0 = c * 256 + g * 32;
        int xr = (c & 7) << 4;
        auto p = (__attribute__((address_space(3))) char*)&ldsb[wid][0][0];
        unsigned base = (unsigned)(size_t)p;
        a0r = base + ((a0 + 0)   ^ xr);
        a1r = base + ((a0 + 16)  ^ xr);
        a2r = base + ((a0 + 128) ^ xr);
        a3r = base + ((a0 + 144) ^ xr);
    }
    // pre-swizzled global source offsets for staging (involution of the above)
    int offs[4];
#pragma unroll
    for (int k = 0; k < 4; ++k) {
        int lin = k * 1024 + lane * 16;
        int row = lin >> 8;
        offs[k] = lin ^ ((row & 7) << 4);
    }

    // monomial exponent selectors for this lane's output column p = c
    const int cp = (c < 10) ? c : 9;
    const int E1[10] = {0,0,0,0,0,0,1,1,1,2};
    const int E2[10] = {0,0,0,1,1,2,1,1,2,2};
    const int E3[10] = {0,1,2,1,2,2,1,2,2,2};
    const int e1 = E1[cp], e2 = E2[cp], e3 = E3[cp];

    f32x4 d2[4];
#pragma unroll
    for (int t = 0; t < 4; ++t) d2[t] = (f32x4){0.f, 0.f, 0.f, 0.f};

    const float C0 = 0.632455532033676f; // sqrt(2/5)
    const float cf1 = (float)(c + 1);
    const int numTiles = N >> 4;         // N % 16 == 0

    auto stage = [&](char* dst, int tile) {
        const char* gb = (const char*)h + (size_t)tile * 4096;
#pragma unroll
        for (int k = 0; k < 4; ++k) glds16(gb + offs[k], dst + k * 1024);
    };

    auto computeTile = [&](f32x4 h00, f32x4 h01, f32x4 h10, f32x4 h11,
                           f32x4 px, f32x4 py, f32x4 pz) {
        bf16x8 Af[2];
#pragma unroll
        for (int e = 0; e < 4; ++e) {
            Af[0][e] = (__bf16)h00[e]; Af[0][4 + e] = (__bf16)h01[e];
            Af[1][e] = (__bf16)h10[e]; Af[1][4 + e] = (__bf16)h11[e];
        }
        f32x4 acc[4];
#pragma unroll
        for (int t = 0; t < 4; ++t) acc[t] = (f32x4){0.f, 0.f, 0.f, 0.f};
#pragma unroll
        for (int jb = 0; jb < 2; ++jb)
#pragma unroll
          for (int t = 0; t < 4; ++t)
            acc[t] = __builtin_amdgcn_mfma_f32_16x16x32_bf16(Af[jb], Bf[t][jb], acc[t], 0, 0, 0);

        float vm[4][4];
        bf16x8 B2;
#pragma unroll
        for (int e = 4; e < 8; ++e) B2[e] = (__bf16)0.0f;
#pragma unroll
        for (int i = 0; i < 4; ++i) {
            float x = px[i], y = py[i], z = pz[i];
            float r2 = x * x + y * y + z * z;
            float inv = rsqrtf(r2);
            float nx = x * inv, ny = y * inv, nz = z * inv;
            float rev1 = (r2 * inv) * 0.1f;   // r/10 revolutions per unit n
            float coef = C0 * inv;            // sqrt(2/5)/r
            float s1 = (e1 == 0) ? nx : ((e1 == 1) ? ny : nz);
            float s2 = (e2 == 0) ? nx : ((e2 == 1) ? ny : nz);
            float s3 = (e3 == 0) ? nx : ((e3 == 1) ? ny : nz);
            B2[i] = (__bf16)(s1 * s2 * s3);
            float revn = cf1 * rev1;
            float rev16 = 16.0f * rev1;
#pragma unroll
            for (int t = 0; t < 4; ++t) {
                float rv = revn - floorf(revn);
                vm[t][i] = __builtin_amdgcn_sinf(rv) * coef;
                revn += rev16;
            }
        }
#pragma unroll
        for (int t = 0; t < 4; ++t) {
            bf16x8 A2;
#pragma unroll
            for (int i = 0; i < 4; ++i) A2[i] = (__bf16)(vm[t][i] * acc[t][i]);
#pragma unroll
            for (int e = 4; e < 8; ++e) A2[e] = (__bf16)0.0f;
            d2[t] = __builtin_amdgcn_mfma_f32_16x16x32_bf16(A2, B2, d2[t], 0, 0, 0);
        }
    };

    // alternating rp prefetch sets (loaded one body ahead; no cross-copies)
    f32x4 Ppx, Ppy, Ppz, Qpx, Qpy, Qpz;

#define RPLOAD(S, t) do {                                   \
        const int ai_ = ((t) << 4) + g * 4;                 \
        S##px = *(const f32x4*)(rp + ai_);                  \
        S##py = *(const f32x4*)(rp + N + ai_);              \
        S##pz = *(const f32x4*)(rp + 2 * N + ai_);          \
    } while (0)

// BODY: consume buffer CURB (tile T, rp set RC), stage tile T+1 into the
// other buffer and rp set RF.  Exactly 7 VMEM ops issued before the wait.
#define BODY(OFFSTR, STBUF, RC, RF, T) do {                                   \
        { int tn_ = (T) + nwave;                                              \
          int st_ = (tn_ < numTiles) ? tn_ : gwave;                           \
          stage(&ldsb[wid][STBUF][0], st_); RPLOAD(RF, st_); }                \
        asm volatile("s_waitcnt vmcnt(7)" ::: "memory");                      \
        f32x4 h00_, h01_, h10_, h11_;                                         \
        asm volatile("ds_read_b128 %0, %1 " OFFSTR : "=&v"(h00_) : "v"(a0r)); \
        asm volatile("ds_read_b128 %0, %1 " OFFSTR : "=&v"(h01_) : "v"(a1r)); \
        asm volatile("ds_read_b128 %0, %1 " OFFSTR : "=&v"(h10_) : "v"(a2r)); \
        asm volatile("ds_read_b128 %0, %1 " OFFSTR : "=&v"(h11_) : "v"(a3r)); \
        asm volatile("s_waitcnt lgkmcnt(0)" ::: "memory");                    \
        __builtin_amdgcn_sched_barrier(0);                                    \
        computeTile(h00_, h01_, h10_, h11_, RC##px, RC##py, RC##pz);          \
    } while (0)

    int tile = gwave;
    if (tile < numTiles) {
        stage(&ldsb[wid][0][0], tile);   // 4 glds -> buf0
        RPLOAD(P, tile);                  // 3 rp  -> set P   (7 outstanding)
        for (;;) {
            BODY("offset:0",    1, P, Q, tile);   // consume buf0/P, stage buf1/Q
            tile += nwave; if (tile >= numTiles) break;
            BODY("offset:4096", 0, Q, P, tile);   // consume buf1/Q, stage buf0/P
            tile += nwave; if (tile >= numTiles) break;
        }
    }
#undef BODY
#undef RPLOAD

    // drain in-flight glds DMA (lands in dead ldsb; belt-and-suspenders)
    asm volatile("s_waitcnt vmcnt(0)" ::: "memory");

    // D2 layout: lane (c,g) holds D[k=16t+g*4+reg][p=c] for c<10
    if (c < 10) {
#pragma unroll
        for (int t = 0; t < 4; ++t)
#pragma unroll
          for (int r = 0; r < 4; ++r)
            Ds[wid][(16 * t + g * 4 + r) * 10 + c] = d2[t][r];
    }
    __syncthreads();
    for (int idx = threadIdx.x; idx < NCH * 10; idx += blockDim.x) {
        float s = Ds[0][idx] + Ds[1][idx] + Ds[2][idx] + Ds[3][idx];
        atomicAdd(&ws[idx], s);
    }
}

// expand 10 symmetric monomials -> 27-entry (x,y,z) tensor per channel
__global__ void ab_expand(const float* __restrict__ ws, float* __restrict__ out) {
    const unsigned char tab[27] = { 0,1,2, 1,3,4, 2,4,5,
                                    1,3,4, 3,6,7, 4,7,8,
                                    2,4,5, 4,7,8, 5,8,9 };
    int i = blockIdx.x * blockDim.x + threadIdx.x;
    if (i < NCH * 27) {
        int k = i / 27, cc = i % 27;
        out[i] = ws[k * 10 + tab[cc]];
    }
}

extern "C" void kernel_launch(void* const* d_in, const int* in_sizes, int n_in,
                              void* d_out, int out_size, void* d_ws, size_t ws_size,
                              hipStream_t stream) {
    const float* h  = (const float*)d_in[0];
    const float* rp = (const float*)d_in[1];
    const float* W  = (const float*)d_in[2];
    float* out = (float*)d_out;
    float* ws  = (float*)d_ws;
    const int N = in_sizes[1] / 3;

    ab_zero<<<1, 640, 0, stream>>>(ws);
    ab_main<<<512, 256, 0, stream>>>(h, rp, W, ws, N);
    ab_expand<<<(NCH * 27 + 255) / 256, 256, 0, stream>>>(ws, out);
}